// Round 13
// baseline (637.684 us; speedup 1.0000x reference)
//
#include <hip/hip_runtime.h>

typedef unsigned short u16;
typedef float f32x4 __attribute__((ext_vector_type(4)));
typedef __bf16 bf16x8 __attribute__((ext_vector_type(8)));
typedef unsigned short u16x8 __attribute__((ext_vector_type(8)));
typedef unsigned short u16x4 __attribute__((ext_vector_type(4)));
typedef unsigned long long ull;

#define N_TOKENS 8192
#define IN_DIM   1024
#define HID_DIM  4096
#define OUT_DIM  1024
#define N_EXP    6

__device__ __forceinline__ u16 f2bf(float f) {
  union { float f; unsigned int u; } v; v.f = f;
  unsigned int u = v.u;
  unsigned int r = (u + 0x7FFFu + ((u >> 16) & 1u)) >> 16;
  return (u16)r;
}

__device__ __forceinline__ float bf2f(u16 v) {
  union { unsigned int u; float f; } x; x.u = ((unsigned int)v) << 16; return x.f;
}

__device__ __forceinline__ void load_lds16(const void* g, void* l) {
  __builtin_amdgcn_global_load_lds(
      (const __attribute__((address_space(1))) void*)g,
      (__attribute__((address_space(3))) void*)l, 16, 0, 0);
}

// ---------------- prep: W1 transpose (blocks 0..6143) + gating/cvt (blocks 6144..8191) ----------------
__global__ __launch_bounds__(256) void prep_kernel(const float* __restrict__ W1,
                                                   u16* __restrict__ W1T,
                                                   const float* __restrict__ x,
                                                   const float* __restrict__ Wg,
                                                   const float* __restrict__ bg,
                                                   u16* __restrict__ xb,
                                                   int* __restrict__ gate_e,
                                                   float* __restrict__ gate_w) {
  __shared__ u16 tile[64][72];
  const int bid = blockIdx.x;
  if (bid < 6144) {
    // W1 [IN][HID] -> W1T [HID][IN], expert = bid>>10, tile = bid&1023 (64x x 16y)
    const int ex = bid >> 10, ti = bid & 1023;
    const float* src = W1 + (size_t)ex * IN_DIM * HID_DIM;
    u16* dst = W1T + (size_t)ex * IN_DIM * HID_DIM;
    const int tx = ti & 63, ty = ti >> 6;
    const int C = HID_DIM, R = IN_DIM;
    int c0 = tx * 64, r0 = ty * 64;
    int t = threadIdx.x;
    int cc = (t & 15) * 4, rb = t >> 4;
#pragma unroll
    for (int p = 0; p < 4; p++) {
      int r = p * 16 + rb;
      float4 v = *(const float4*)(src + (size_t)(r0 + r) * C + c0 + cc);
      tile[cc + 0][r] = f2bf(v.x);
      tile[cc + 1][r] = f2bf(v.y);
      tile[cc + 2][r] = f2bf(v.z);
      tile[cc + 3][r] = f2bf(v.w);
    }
    __syncthreads();
    int c = t >> 2, rp = (t & 3) * 16;
    u16* dp = dst + (size_t)(c0 + c) * R + r0 + rp;
    *(u16x8*)(dp)     = *(const u16x8*)&tile[c][rp];
    *(u16x8*)(dp + 8) = *(const u16x8*)&tile[c][rp + 8];
    return;
  }
  // ---- gating part ----
  const int gb = bid - 6144;
  int lane = threadIdx.x & 63, wid = threadIdx.x >> 6;
  int tok = gb * 4 + wid;
  float acc[N_EXP] = {0.f, 0.f, 0.f, 0.f, 0.f, 0.f};
  const float4* xr = (const float4*)(x + (size_t)tok * IN_DIM);
  u16* xw = xb + (size_t)tok * IN_DIM;
#pragma unroll
  for (int g = 0; g < 4; g++) {
    float4 v = xr[lane + g * 64];
    int c0 = (lane + g * 64) * 4;
    u16x4 o; o[0] = f2bf(v.x); o[1] = f2bf(v.y); o[2] = f2bf(v.z); o[3] = f2bf(v.w);
    *(u16x4*)(xw + c0) = o;
#pragma unroll
    for (int c = 0; c < 4; c++) {
      float xv = (c == 0) ? v.x : (c == 1) ? v.y : (c == 2) ? v.z : v.w;
      const float* wr = Wg + (c0 + c) * N_EXP;
#pragma unroll
      for (int e = 0; e < N_EXP; e++) acc[e] += xv * wr[e];
    }
  }
#pragma unroll
  for (int e = 0; e < N_EXP; e++) {
    float a = acc[e];
#pragma unroll
    for (int off = 32; off > 0; off >>= 1) a += __shfl_xor(a, off, 64);
    acc[e] = a;
  }
  if (lane == 0) {
    float s[N_EXP];
#pragma unroll
    for (int e = 0; e < N_EXP; e++) s[e] = acc[e] + bg[e];
    float mx = s[0];
#pragma unroll
    for (int e = 1; e < N_EXP; e++) mx = fmaxf(mx, s[e]);
    float p[N_EXP], sum = 0.f;
#pragma unroll
    for (int e = 0; e < N_EXP; e++) { p[e] = expf(s[e] - mx); sum += p[e]; }
    int a = 0;
#pragma unroll
    for (int e = 1; e < N_EXP; e++) if (s[e] > s[a]) a = e;
    int b = (a == 0) ? 1 : 0;
#pragma unroll
    for (int e = 0; e < N_EXP; e++) if (e != a && s[e] > s[b]) b = e;
    float pa = p[a] / sum, pb = p[b] / sum;
    float den = pa + pb + 1e-8f;
    gate_e[2 * tok] = a; gate_e[2 * tok + 1] = b;
    gate_w[2 * tok] = pa / den; gate_w[2 * tok + 1] = pb / den;
  }
}

// ---------------- routing: ballot compaction, 2 tokens/lane + 1-deep prefetch ----------------
__global__ __launch_bounds__(384) void routing_kernel(const int* __restrict__ gate_e,
                                                      int* __restrict__ idxl,
                                                      int* __restrict__ tokslot,
                                                      int* __restrict__ meta) {
  int wave = threadIdx.x >> 6, lane = threadIdx.x & 63;
  __shared__ int s_cnt[N_EXP];
  if (wave < N_EXP) {
    const int e = wave;
    int cnt = 0;
    const int4* gp = (const int4*)gate_e;
    int4 g = gp[lane];
    const ull below = (1ull << lane) - 1ull;
    for (int it = 0; it < N_TOKENS / 128; it++) {
      int4 gn;
      if (it + 1 < N_TOKENS / 128) gn = gp[(it + 1) * 64 + lane];
      bool s0 = (g.x == e) || (g.y == e);
      bool s1 = (g.z == e) || (g.w == e);
      ull m0 = __ballot(s0), m1 = __ballot(s1);
      int p0 = __popcll(m0 & below) + __popcll(m1 & below);
      int t0 = it * 128 + 2 * lane;
      if (s0) {
        int j = cnt + p0;
        idxl[e * N_TOKENS + j] = t0;
        tokslot[2 * t0 + ((g.x == e) ? 0 : 1)] = j;
      }
      if (s1) {
        int j = cnt + p0 + (s0 ? 1 : 0);
        idxl[e * N_TOKENS + j] = t0 + 1;
        tokslot[2 * (t0 + 1) + ((g.z == e) ? 0 : 1)] = j;
      }
      cnt += __popcll(m0) + __popcll(m1);
      g = gn;
    }
    if (lane == 0) s_cnt[e] = cnt;
  }
  __syncthreads();
  if (threadIdx.x == 0) {
    int off = 0;
    for (int e = 0; e < N_EXP; e++) { meta[e] = s_cnt[e]; meta[8 + e] = off; off += s_cnt[e]; }
    meta[8 + N_EXP] = off;
  }
}

// ========== 256x256 GEMM core, BK=64, DEEP-COUNTED schedule (race-free rework of r8) ==========
// 8 waves. LDS sA/sB[2][256*64] = 128 KB. Tile t uses buf c=t&1.
// Stage map during tile t: phi1 -> t+1.B1 into buf c^1; phi2 -> t+2.A0 into buf c;
// phi3 -> (none); phi4 -> t+2.B0 + t+2.A1 into buf c. Single vmcnt(6) at phi4-end:
// outstanding <= 14; newest 6 = t+2's {A0,B0,A1}; completes through t+1.B1 = ALL of
// tile t+1 (issue->wait cover 3-6 phases). WAR safety: every stage targets a region
// whose reads completed at a PRECEDING barrier (A0 read phi1 only; B0 read phi1/phi3,
// staged phi4; A1 read phi3, staged phi4; B1(cur) never staged by tile t).
// No phase reads and stages the same region (the r8 race, removed).
// Prologue: t0 full (8) + t1.{A0,B0,A1} (6); vmcnt(6) -> t0 complete.
// XOR swizzle: LDS(r, c16) holds global (r, c16 ^ (r&7)); stage source chunk
// (lane&7)^(lane>>3); read chunk (k16 ^ (lane&7)). Verified 0 bank conflicts.

#define GDS_A(AH) \
  _Pragma("unroll") for (int mi = 0; mi < 4; mi++) { \
    int r_ = (AH)*128 + wr*64 + mi*16 + lrow; \
    af[mi][0] = *(const bf16x8*)&sA[cur][r_*64 + ((lhi ^ lx7) * 8)]; \
    af[mi][1] = *(const bf16x8*)&sA[cur][r_*64 + (((4 + lhi) ^ lx7) * 8)]; }

#define GDS_B(BH) \
  _Pragma("unroll") for (int nj = 0; nj < 2; nj++) { \
    int r_ = (BH)*128 + wc*32 + nj*16 + lrow; \
    bfr[nj][0] = *(const bf16x8*)&sB[cur][r_*64 + ((lhi ^ lx7) * 8)]; \
    bfr[nj][1] = *(const bf16x8*)&sB[cur][r_*64 + (((4 + lhi) ^ lx7) * 8)]; }

#define STG_A(BUF, HH, KS) \
  load_lds16(pa[HH][0] + (KS), &sA[BUF][((HH)*128 + wave*16) * 64]); \
  load_lds16(pa[HH][1] + (KS), &sA[BUF][((HH)*128 + wave*16 + 8) * 64]);

#define STG_B(BUF, HH, KS) \
  load_lds16(pb[HH][0] + (KS), &sB[BUF][((HH)*128 + wave*16) * 64]); \
  load_lds16(pb[HH][1] + (KS), &sB[BUF][((HH)*128 + wave*16 + 8) * 64]);

#define GMFMA_Q(AH, BH) \
  _Pragma("unroll") for (int mi = 0; mi < 4; mi++) \
  _Pragma("unroll") for (int nj = 0; nj < 2; nj++) { \
    acc[AH][BH][mi][nj] = __builtin_amdgcn_mfma_f32_16x16x32_bf16(af[mi][0], bfr[nj][0], acc[AH][BH][mi][nj], 0, 0, 0); \
    acc[AH][BH][mi][nj] = __builtin_amdgcn_mfma_f32_16x16x32_bf16(af[mi][1], bfr[nj][1], acc[AH][BH][mi][nj], 0, 0, 0); }

#define GBAR __builtin_amdgcn_s_barrier()
#define GLGKM0 asm volatile("s_waitcnt lgkmcnt(0)" ::: "memory")
#define GVMC(n) asm volatile("s_waitcnt vmcnt(" #n ")" ::: "memory")
#define GPRIO1 __builtin_amdgcn_s_setprio(1)
#define GPRIO0 __builtin_amdgcn_s_setprio(0)

#define GEMM_KLOOP(NT_)                                                        \
  { STG_A(0, 0, 0) STG_B(0, 0, 0) STG_A(0, 1, 0) STG_B(0, 1, 0)                \
    STG_A(1, 0, 64) STG_B(1, 0, 64) STG_A(1, 1, 64) }                          \
  GVMC(6);                                                                     \
  GBAR;                                                                        \
  for (int t = 0; t < (NT_); t++) {                                            \
    const int cur = t & 1, nxt = cur ^ 1;                                      \
    const int kB1 = ((t + 1 < (NT_)) ? (t + 1) : ((NT_) - 1)) * 64;            \
    const int k2  = ((t + 2 < (NT_)) ? (t + 2) : ((NT_) - 1)) * 64;            \
    /* phase 1: Q(0,0); stage (t+1).B1 -> buf[nxt] */                          \
    GDS_A(0); GDS_B(0);                                                        \
    STG_B(nxt, 1, kB1)                                                         \
    GBAR; GLGKM0;                                                              \
    GPRIO1; GMFMA_Q(0, 0); GPRIO0;                                             \
    GBAR;                                                                      \
    /* phase 2: Q(0,1); stage (t+2).A0 -> buf[cur] (A0 reads closed phi1) */   \
    GDS_B(1);                                                                  \
    STG_A(cur, 0, k2)                                                          \
    GBAR; GLGKM0;                                                              \
    GPRIO1; GMFMA_Q(0, 1); GPRIO0;                                             \
    GBAR;                                                                      \
    /* phase 3: Q(1,0); no stage (B0 re-read lives here) */                    \
    GDS_A(1); GDS_B(0);                                                        \
    GBAR; GLGKM0;                                                              \
    GPRIO1; GMFMA_Q(1, 0); GPRIO0;                                             \
    GBAR;                                                                      \
    /* phase 4: Q(1,1); stage (t+2).B0,A1 -> buf[cur] (reads closed phi3) */   \
    GDS_B(1);                                                                  \
    STG_B(cur, 0, k2) STG_A(cur, 1, k2)                                        \
    GBAR; GLGKM0;                                                              \
    GPRIO1; GMFMA_Q(1, 1); GPRIO0;                                             \
    GVMC(6); GBAR;                                                             \
  }

// Expert decode from padded global M-tile id (72 padded tiles of 256 rows)
__device__ __forceinline__ void decode_expert(const int* meta, int mtg,
                                              int& e, int& mt, int& cnt) {
  e = -1; mt = 0; cnt = 0;
  int sum = 0;
#pragma unroll
  for (int ee = 0; ee < N_EXP; ee++) {
    int c = meta[ee];
    int nt = (c + 255) >> 8;
    if (e < 0 && mtg < sum + nt) { e = ee; mt = mtg - sum; cnt = c; }
    sum += nt;
  }
}

// ---------------- grouped GEMM1: h = relu(x_gathered @ W1 + b1), bf16 out ----------------
// Blocks [0,1152): XCD-chunked GEMM (16n x 72m). Blocks [1152,7296): W2
// transpose tiles (fill the GEMM tail rounds; W2T region is disjoint from all
// gemm1-live buffers; dispatch order guarantees they run after GEMM blocks).
__global__ __launch_bounds__(512) void gemm1_kernel(const u16* __restrict__ xb,
                                                    const u16* __restrict__ W1T,
                                                    const float* __restrict__ b1,
                                                    const int* __restrict__ idxl,
                                                    const int* __restrict__ meta,
                                                    u16* __restrict__ h,
                                                    const float* __restrict__ W2,
                                                    u16* __restrict__ W2T) {
  __shared__ u16 sA[2][16384];
  __shared__ u16 sB[2][16384];
  const int bid = blockIdx.x;
  if (bid >= 1152) {
    // ---- W2 transpose tile: W2[ex] [HID][OUT] f32 -> W2T[ex] [OUT][HID] bf16 ----
    u16 (*tile)[72] = (u16(*)[72])&sA[0][0];
    const int ti = bid - 1152;           // [0, 6144)
    const int ex = ti >> 10;             // 1024 tiles per expert (16x x 64y)
    const int t2 = ti & 1023;
    const int tx = t2 & 15, ty = t2 >> 4;
    const float* src = W2 + (size_t)ex * HID_DIM * OUT_DIM;
    u16* dst = W2T + (size_t)ex * HID_DIM * OUT_DIM;
    const int C = OUT_DIM, R = HID_DIM;
    const int c0 = tx * 64, r0 = ty * 64;
    const int t = threadIdx.x;
    const int cc = (t & 15) * 4, rb = t >> 4;   // rb in [0,32)
#pragma unroll
    for (int p = 0; p < 2; p++) {
      int r = p * 32 + rb;
      float4 v = *(const float4*)(src + (size_t)(r0 + r) * C + c0 + cc);
      tile[cc + 0][r] = f2bf(v.x);
      tile[cc + 1][r] = f2bf(v.y);
      tile[cc + 2][r] = f2bf(v.z);
      tile[cc + 3][r] = f2bf(v.w);
    }
    __syncthreads();
    const int c = t >> 3, rp = (t & 7) * 8;
    *(u16x8*)(dst + (size_t)(c0 + c) * R + r0 + rp) = *(const u16x8*)&tile[c][rp];
    return;
  }
  const int xcd = bid & 7;
  const int s = bid >> 3;            // [0,144)
  const int chunk = s / 36, q = s % 36;
  const int n = chunk * 4 + (q & 3); // [0,16)
  const int mtg = xcd * 9 + (q >> 2);

  int e, mt, cnt;
  decode_expert(meta, mtg, e, mt, cnt);
  if (e < 0) return;
  const int off = meta[8 + e];
  const int bn0 = n * 256;
  const int tid = threadIdx.x, lane = tid & 63, wave = tid >> 6;
  const int wr = wave >> 2, wc = wave & 3;
  const int lrow = lane & 15, lhi = lane >> 4, lx7 = lane & 7;
  const int schunk = (lane & 7) ^ (lane >> 3);

  const u16* pa[2][2];
  const u16* pb[2][2];
  const u16* bbase = W1T + (size_t)e * HID_DIM * IN_DIM;
#pragma unroll
  for (int hh = 0; hh < 2; hh++)
#pragma unroll
    for (int i = 0; i < 2; i++) {
      int gr = hh * 128 + wave * 16 + i * 8 + (lane >> 3);
      int j = mt * 256 + gr; if (j >= cnt) j = cnt - 1;
      int tok = idxl[e * N_TOKENS + j];
      pa[hh][i] = xb + (size_t)tok * IN_DIM + schunk * 8;
      pb[hh][i] = bbase + (size_t)(bn0 + gr) * IN_DIM + schunk * 8;
    }

  f32x4 acc[2][2][4][2] = {};
  bf16x8 af[4][2], bfr[2][2];

  GEMM_KLOOP(IN_DIM / 64)

  // epilogue: relu(acc + b1) -> h (bf16)
#pragma unroll
  for (int ah = 0; ah < 2; ah++)
#pragma unroll
    for (int bh = 0; bh < 2; bh++)
#pragma unroll
      for (int nj = 0; nj < 2; nj++) {
        int col = bn0 + bh * 128 + wc * 32 + nj * 16 + lrow;
        float bias = b1[e * HID_DIM + col];
#pragma unroll
        for (int mi = 0; mi < 4; mi++)
#pragma unroll
          for (int rr = 0; rr < 4; rr++) {
            int j = mt * 256 + ah * 128 + wr * 64 + mi * 16 + lhi * 4 + rr;
            if (j < cnt) {
              float v = fmaxf(acc[ah][bh][mi][nj][rr] + bias, 0.f);
              h[(size_t)(off + j) * HID_DIM + col] = f2bf(v);
            }
          }
      }
}

// ---------------- grouped GEMM2: y_kz = (h @ W2 [+ b2 if kz==0]) as bf16, NO atomics ----------------
// XCD-chunked 1D grid (576 = 8v x 72m, v=(n,kz))
__global__ __launch_bounds__(512) void gemm2_kernel(const u16* __restrict__ hbuf,
                                                    const u16* __restrict__ W2T,
                                                    const float* __restrict__ b2,
                                                    const int* __restrict__ meta,
                                                    u16* __restrict__ y0,
                                                    u16* __restrict__ y1) {
  __shared__ u16 sA[2][16384];
  __shared__ u16 sB[2][16384];
  const int bid = blockIdx.x;
  const int xcd = bid & 7;
  const int s = bid >> 3;       // [0,72)
  const int v = s & 7;          // (n,kz) sibling, fastest
  const int mtg = xcd * 9 + (s >> 3);
  const int n = v >> 1, kzid = v & 1;

  int e, mt, cnt;
  decode_expert(meta, mtg, e, mt, cnt);
  if (e < 0) return;
  const int off = meta[8 + e];
  const int bn0 = n * 256;
  const int kz = kzid * (HID_DIM / 2);
  const int tid = threadIdx.x, lane = tid & 63, wave = tid >> 6;
  const int wr = wave >> 2, wc = wave & 3;
  const int lrow = lane & 15, lhi = lane >> 4, lx7 = lane & 7;
  const int schunk = (lane & 7) ^ (lane >> 3);

  const u16* pa[2][2];
  const u16* pb[2][2];
  const u16* bbase = W2T + (size_t)e * OUT_DIM * HID_DIM;
#pragma unroll
  for (int hh = 0; hh < 2; hh++)
#pragma unroll
    for (int i = 0; i < 2; i++) {
      int gr = hh * 128 + wave * 16 + i * 8 + (lane >> 3);
      int j = mt * 256 + gr; if (j >= cnt) j = cnt - 1;
      pa[hh][i] = hbuf + (size_t)(off + j) * HID_DIM + kz + schunk * 8;
      pb[hh][i] = bbase + (size_t)(bn0 + gr) * HID_DIM + kz + schunk * 8;
    }

  f32x4 acc[2][2][4][2] = {};
  bf16x8 af[4][2], bfr[2][2];

  GEMM_KLOOP(HID_DIM / 2 / 64)

  // epilogue: plain coalesced bf16 stores into the kz-specific y buffer
  u16* __restrict__ yb = kzid ? y1 : y0;
#pragma unroll
  for (int ah = 0; ah < 2; ah++)
#pragma unroll
    for (int bh = 0; bh < 2; bh++)
#pragma unroll
      for (int nj = 0; nj < 2; nj++) {
        int col = bn0 + bh * 128 + wc * 32 + nj * 16 + lrow;
        float bias = (kzid == 0) ? b2[e * OUT_DIM + col] : 0.f;
#pragma unroll
        for (int mi = 0; mi < 4; mi++)
#pragma unroll
          for (int rr = 0; rr < 4; rr++) {
            int j = mt * 256 + ah * 128 + wr * 64 + mi * 16 + lhi * 4 + rr;
            if (j < cnt)
              yb[(size_t)(off + j) * OUT_DIM + col] = f2bf(acc[ah][bh][mi][nj][rr] + bias);
          }
      }
}

// ---------------- combine: out[t] = sum_k w_k * (y0[slot_k] + y1[slot_k]) ----------------
__global__ __launch_bounds__(256) void combine_kernel(const u16* __restrict__ y0,
                                                      const u16* __restrict__ y1,
                                                      const int* __restrict__ gate_e,
                                                      const float* __restrict__ gate_w,
                                                      const int* __restrict__ tokslot,
                                                      const int* __restrict__ meta,
                                                      float* __restrict__ out) {
  const int t = blockIdx.x;
  const int e0 = gate_e[2 * t], e1 = gate_e[2 * t + 1];
  const float w0 = gate_w[2 * t], w1 = gate_w[2 * t + 1];
  const size_t s0 = (size_t)(meta[8 + e0] + tokslot[2 * t]) * OUT_DIM;
  const size_t s1 = (size_t)(meta[8 + e1] + tokslot[2 * t + 1]) * OUT_DIM;
  const int c = threadIdx.x * 4;
  u16x4 a0 = *(const u16x4*)(y0 + s0 + c);
  u16x4 b0 = *(const u16x4*)(y1 + s0 + c);
  u16x4 a1 = *(const u16x4*)(y0 + s1 + c);
  u16x4 b1 = *(const u16x4*)(y1 + s1 + c);
  float4 o;
  o.x = w0 * (bf2f(a0[0]) + bf2f(b0[0])) + w1 * (bf2f(a1[0]) + bf2f(b1[0]));
  o.y = w0 * (bf2f(a0[1]) + bf2f(b0[1])) + w1 * (bf2f(a1[1]) + bf2f(b1[1]));
  o.z = w0 * (bf2f(a0[2]) + bf2f(b0[2])) + w1 * (bf2f(a1[2]) + bf2f(b1[2]));
  o.w = w0 * (bf2f(a0[3]) + bf2f(b0[3])) + w1 * (bf2f(a1[3]) + bf2f(b1[3]));
  *(float4*)(out + (size_t)t * OUT_DIM + c) = o;
}

extern "C" void kernel_launch(void* const* d_in, const int* in_sizes, int n_in,
                              void* d_out, int out_size, void* d_ws, size_t ws_size,
                              hipStream_t stream) {
  const float* x  = (const float*)d_in[0];
  const float* Wg = (const float*)d_in[1];
  const float* bg = (const float*)d_in[2];
  const float* W1 = (const float*)d_in[3];
  const float* b1 = (const float*)d_in[4];
  const float* W2 = (const float*)d_in[5];
  const float* b2 = (const float*)d_in[6];
  float* out = (float*)d_out;

  char* ws = (char*)d_ws;
  // ws layout (bytes), r10-proven. y0/y1 ALIAS xb+W1T (dead after gemm1).
  u16*   xb     = (u16*)(ws);                         // 16,777,216   [live: prep..gemm1]
  u16*   W1T    = (u16*)(ws + 16777216);              // 50,331,648   [live: prep..gemm1]
  u16*   y0     = (u16*)(ws);                         // 33,554,432   [live: gemm2..combine]
  u16*   y1     = (u16*)(ws + 33554432);              // 33,554,432   [live: gemm2..combine]
  u16*   W2T    = (u16*)(ws + 67108864);              // 50,331,648   [written in gemm1 tail blocks]
  u16*   h      = (u16*)(ws + 117440512);             // 134,217,728
  int*   gate_e = (int*)(ws + 251658240);             // 65,536
  float* gate_w = (float*)(ws + 251723776);           // 65,536
  int*   idxl   = (int*)(ws + 251789312);             // 196,608
  int*   tokslot= (int*)(ws + 251985920);             // 65,536
  int*   meta   = (int*)(ws + 252051456);             // 64

  // prep: W1 transpose (6144 blocks) + gating/cvt (2048 blocks)
  prep_kernel<<<8192, 256, 0, stream>>>(W1, W1T, x, Wg, bg, xb, gate_e, gate_w);
  routing_kernel<<<1, 384, 0, stream>>>(gate_e, idxl, tokslot, meta);
  // gemm1: 1152 GEMM blocks + 6144 W2-transpose blocks (tail-filled)
  gemm1_kernel<<<7296, 512, 0, stream>>>(xb, W1T, b1, idxl, meta, h, W2, W2T);
  // gemm2: 8 (n,kz) x 72 padded m-tiles, XCD-chunked 1D; writes y0/y1
  gemm2_kernel<<<576, 512, 0, stream>>>(h, W2T, b2, meta, y0, y1);
  // combine: one block per token
  combine_kernel<<<N_TOKENS, 256, 0, stream>>>(y0, y1, gate_e, gate_w, tokslot, meta, out);
}

// Round 14
// 532.575 us; speedup vs baseline: 1.1974x; 1.1974x over previous
//
#include <hip/hip_runtime.h>

typedef unsigned short u16;
typedef float f32x4 __attribute__((ext_vector_type(4)));
typedef __bf16 bf16x8 __attribute__((ext_vector_type(8)));
typedef unsigned short u16x8 __attribute__((ext_vector_type(8)));
typedef unsigned short u16x4 __attribute__((ext_vector_type(4)));
typedef unsigned long long ull;

#define N_TOKENS 8192
#define IN_DIM   1024
#define HID_DIM  4096
#define OUT_DIM  1024
#define N_EXP    6

__device__ __forceinline__ u16 f2bf(float f) {
  union { float f; unsigned int u; } v; v.f = f;
  unsigned int u = v.u;
  unsigned int r = (u + 0x7FFFu + ((u >> 16) & 1u)) >> 16;
  return (u16)r;
}

__device__ __forceinline__ float bf2f(u16 v) {
  union { unsigned int u; float f; } x; x.u = ((unsigned int)v) << 16; return x.f;
}

__device__ __forceinline__ void load_lds16(const void* g, void* l) {
  __builtin_amdgcn_global_load_lds(
      (const __attribute__((address_space(1))) void*)g,
      (__attribute__((address_space(3))) void*)l, 16, 0, 0);
}

// ---------------- prep: W1 transpose (blocks 0..6143) + gating/cvt (blocks 6144..8191) ----------------
__global__ __launch_bounds__(256) void prep_kernel(const float* __restrict__ W1,
                                                   u16* __restrict__ W1T,
                                                   const float* __restrict__ x,
                                                   const float* __restrict__ Wg,
                                                   const float* __restrict__ bg,
                                                   u16* __restrict__ xb,
                                                   int* __restrict__ gate_e,
                                                   float* __restrict__ gate_w) {
  __shared__ u16 tile[64][72];
  const int bid = blockIdx.x;
  if (bid < 6144) {
    // W1 [IN][HID] -> W1T [HID][IN], expert = bid>>10, tile = bid&1023 (64x x 16y)
    const int ex = bid >> 10, ti = bid & 1023;
    const float* src = W1 + (size_t)ex * IN_DIM * HID_DIM;
    u16* dst = W1T + (size_t)ex * IN_DIM * HID_DIM;
    const int tx = ti & 63, ty = ti >> 6;
    const int C = HID_DIM, R = IN_DIM;
    int c0 = tx * 64, r0 = ty * 64;
    int t = threadIdx.x;
    int cc = (t & 15) * 4, rb = t >> 4;
#pragma unroll
    for (int p = 0; p < 4; p++) {
      int r = p * 16 + rb;
      float4 v = *(const float4*)(src + (size_t)(r0 + r) * C + c0 + cc);
      tile[cc + 0][r] = f2bf(v.x);
      tile[cc + 1][r] = f2bf(v.y);
      tile[cc + 2][r] = f2bf(v.z);
      tile[cc + 3][r] = f2bf(v.w);
    }
    __syncthreads();
    int c = t >> 2, rp = (t & 3) * 16;
    u16* dp = dst + (size_t)(c0 + c) * R + r0 + rp;
    *(u16x8*)(dp)     = *(const u16x8*)&tile[c][rp];
    *(u16x8*)(dp + 8) = *(const u16x8*)&tile[c][rp + 8];
    return;
  }
  // ---- gating part ----
  const int gb = bid - 6144;
  int lane = threadIdx.x & 63, wid = threadIdx.x >> 6;
  int tok = gb * 4 + wid;
  float acc[N_EXP] = {0.f, 0.f, 0.f, 0.f, 0.f, 0.f};
  const float4* xr = (const float4*)(x + (size_t)tok * IN_DIM);
  u16* xw = xb + (size_t)tok * IN_DIM;
#pragma unroll
  for (int g = 0; g < 4; g++) {
    float4 v = xr[lane + g * 64];
    int c0 = (lane + g * 64) * 4;
    u16x4 o; o[0] = f2bf(v.x); o[1] = f2bf(v.y); o[2] = f2bf(v.z); o[3] = f2bf(v.w);
    *(u16x4*)(xw + c0) = o;
#pragma unroll
    for (int c = 0; c < 4; c++) {
      float xv = (c == 0) ? v.x : (c == 1) ? v.y : (c == 2) ? v.z : v.w;
      const float* wr = Wg + (c0 + c) * N_EXP;
#pragma unroll
      for (int e = 0; e < N_EXP; e++) acc[e] += xv * wr[e];
    }
  }
#pragma unroll
  for (int e = 0; e < N_EXP; e++) {
    float a = acc[e];
#pragma unroll
    for (int off = 32; off > 0; off >>= 1) a += __shfl_xor(a, off, 64);
    acc[e] = a;
  }
  if (lane == 0) {
    float s[N_EXP];
#pragma unroll
    for (int e = 0; e < N_EXP; e++) s[e] = acc[e] + bg[e];
    float mx = s[0];
#pragma unroll
    for (int e = 1; e < N_EXP; e++) mx = fmaxf(mx, s[e]);
    float p[N_EXP], sum = 0.f;
#pragma unroll
    for (int e = 0; e < N_EXP; e++) { p[e] = expf(s[e] - mx); sum += p[e]; }
    int a = 0;
#pragma unroll
    for (int e = 1; e < N_EXP; e++) if (s[e] > s[a]) a = e;
    int b = (a == 0) ? 1 : 0;
#pragma unroll
    for (int e = 0; e < N_EXP; e++) if (e != a && s[e] > s[b]) b = e;
    float pa = p[a] / sum, pb = p[b] / sum;
    float den = pa + pb + 1e-8f;
    gate_e[2 * tok] = a; gate_e[2 * tok + 1] = b;
    gate_w[2 * tok] = pa / den; gate_w[2 * tok + 1] = pb / den;
  }
}

// ---------------- routing: ballot compaction, 2 tokens/lane + 1-deep prefetch ----------------
__global__ __launch_bounds__(384) void routing_kernel(const int* __restrict__ gate_e,
                                                      int* __restrict__ idxl,
                                                      int* __restrict__ tokslot,
                                                      int* __restrict__ meta) {
  int wave = threadIdx.x >> 6, lane = threadIdx.x & 63;
  __shared__ int s_cnt[N_EXP];
  if (wave < N_EXP) {
    const int e = wave;
    int cnt = 0;
    const int4* gp = (const int4*)gate_e;
    int4 g = gp[lane];
    const ull below = (1ull << lane) - 1ull;
    for (int it = 0; it < N_TOKENS / 128; it++) {
      int4 gn;
      if (it + 1 < N_TOKENS / 128) gn = gp[(it + 1) * 64 + lane];
      bool s0 = (g.x == e) || (g.y == e);
      bool s1 = (g.z == e) || (g.w == e);
      ull m0 = __ballot(s0), m1 = __ballot(s1);
      int p0 = __popcll(m0 & below) + __popcll(m1 & below);
      int t0 = it * 128 + 2 * lane;
      if (s0) {
        int j = cnt + p0;
        idxl[e * N_TOKENS + j] = t0;
        tokslot[2 * t0 + ((g.x == e) ? 0 : 1)] = j;
      }
      if (s1) {
        int j = cnt + p0 + (s0 ? 1 : 0);
        idxl[e * N_TOKENS + j] = t0 + 1;
        tokslot[2 * (t0 + 1) + ((g.z == e) ? 0 : 1)] = j;
      }
      cnt += __popcll(m0) + __popcll(m1);
      g = gn;
    }
    if (lane == 0) s_cnt[e] = cnt;
  }
  __syncthreads();
  if (threadIdx.x == 0) {
    int off = 0;
    for (int e = 0; e < N_EXP; e++) { meta[e] = s_cnt[e]; meta[8 + e] = off; off += s_cnt[e]; }
    meta[8 + N_EXP] = off;
  }
}

// ================= 256x256 8-phase GEMM core (r3 schedule — race-free, best measured) =================
// BM=BN=256, BK=64, 8 waves. LDS: sA/sB [2][256*64] u16 = 128 KB total.
// ALL stages target buf[nxt]; vmcnt(2)@phi1-end, vmcnt(4)@phi4-end.
// XOR swizzle: LDS(r, c16) holds global (r, c16 ^ (r&7)); stage source chunk
// (lane&7)^(lane>>3); read chunk (k16 ^ (lane&7)). Verified 0 bank conflicts.

#define GDS_A(AH) \
  _Pragma("unroll") for (int mi = 0; mi < 4; mi++) { \
    int r_ = (AH)*128 + wr*64 + mi*16 + lrow; \
    af[mi][0] = *(const bf16x8*)&sA[cur][r_*64 + ((lhi ^ lx7) * 8)]; \
    af[mi][1] = *(const bf16x8*)&sA[cur][r_*64 + (((4 + lhi) ^ lx7) * 8)]; }

#define GDS_B(BH) \
  _Pragma("unroll") for (int nj = 0; nj < 2; nj++) { \
    int r_ = (BH)*128 + wc*32 + nj*16 + lrow; \
    bfr[nj][0] = *(const bf16x8*)&sB[cur][r_*64 + ((lhi ^ lx7) * 8)]; \
    bfr[nj][1] = *(const bf16x8*)&sB[cur][r_*64 + (((4 + lhi) ^ lx7) * 8)]; }

#define GSTG_A(HH) \
  load_lds16(pa[HH][0] + ksn, &sA[nxt][((HH)*128 + wave*16) * 64]); \
  load_lds16(pa[HH][1] + ksn, &sA[nxt][((HH)*128 + wave*16 + 8) * 64]);

#define GSTG_B(HH) \
  load_lds16(pb[HH][0] + ksn, &sB[nxt][((HH)*128 + wave*16) * 64]); \
  load_lds16(pb[HH][1] + ksn, &sB[nxt][((HH)*128 + wave*16 + 8) * 64]);

#define GMFMA_Q(AH, BH) \
  _Pragma("unroll") for (int mi = 0; mi < 4; mi++) \
  _Pragma("unroll") for (int nj = 0; nj < 2; nj++) { \
    acc[AH][BH][mi][nj] = __builtin_amdgcn_mfma_f32_16x16x32_bf16(af[mi][0], bfr[nj][0], acc[AH][BH][mi][nj], 0, 0, 0); \
    acc[AH][BH][mi][nj] = __builtin_amdgcn_mfma_f32_16x16x32_bf16(af[mi][1], bfr[nj][1], acc[AH][BH][mi][nj], 0, 0, 0); }

#define GBAR __builtin_amdgcn_s_barrier()
#define GLGKM0 asm volatile("s_waitcnt lgkmcnt(0)" ::: "memory")
#define GVMC(n) asm volatile("s_waitcnt vmcnt(" #n ")" ::: "memory")

#define GEMM_KLOOP(NT_)                                                        \
  { const int ksn = 0; const int nxt = 0;                                      \
    GSTG_A(0); GSTG_B(0); GSTG_A(1); GSTG_B(1); }                              \
  GVMC(4);                                                                     \
  GBAR;                                                                        \
  int cur = 0;                                                                 \
  for (int t = 0; t < (NT_); t++) {                                            \
    const int nxt = cur ^ 1;                                                   \
    const int ksn = ((t + 1 < (NT_)) ? (t + 1) : ((NT_) - 1)) * 64;            \
    /* phase 1: Q(0,0) */                                                      \
    GDS_A(0); GDS_B(0);                                                        \
    GSTG_A(0);                                                                 \
    GBAR; GLGKM0;                                                              \
    __builtin_amdgcn_s_setprio(1); GMFMA_Q(0, 0); __builtin_amdgcn_s_setprio(0); \
    GVMC(2); GBAR;                                                             \
    /* phase 2: Q(0,1) */                                                      \
    GDS_B(1);                                                                  \
    GSTG_B(0);                                                                 \
    GBAR; GLGKM0;                                                              \
    __builtin_amdgcn_s_setprio(1); GMFMA_Q(0, 1); __builtin_amdgcn_s_setprio(0); \
    GBAR;                                                                      \
    /* phase 3: Q(1,0) */                                                      \
    GDS_A(1); GDS_B(0);                                                        \
    GSTG_A(1);                                                                 \
    GBAR; GLGKM0;                                                              \
    __builtin_amdgcn_s_setprio(1); GMFMA_Q(1, 0); __builtin_amdgcn_s_setprio(0); \
    GBAR;                                                                      \
    /* phase 4: Q(1,1) */                                                      \
    GDS_B(1);                                                                  \
    GSTG_B(1);                                                                 \
    GBAR; GLGKM0;                                                              \
    __builtin_amdgcn_s_setprio(1); GMFMA_Q(1, 1); __builtin_amdgcn_s_setprio(0); \
    GVMC(4); GBAR;                                                             \
    cur = nxt;                                                                 \
  }

// Expert decode from padded global M-tile id (72 padded tiles of 256 rows)
__device__ __forceinline__ void decode_expert(const int* meta, int mtg,
                                              int& e, int& mt, int& cnt) {
  e = -1; mt = 0; cnt = 0;
  int sum = 0;
#pragma unroll
  for (int ee = 0; ee < N_EXP; ee++) {
    int c = meta[ee];
    int nt = (c + 255) >> 8;
    if (e < 0 && mtg < sum + nt) { e = ee; mt = mtg - sum; cnt = c; }
    sum += nt;
  }
}

// ---------------- grouped GEMM1: h = relu(x_gathered @ W1 + b1), bf16 out ----------------
// Blocks [0,1152): XCD-chunked GEMM (16n x 72m). Blocks [1152,7296): W2
// transpose tiles (fill the GEMM tail rounds; W2T region is disjoint from all
// gemm1-live buffers; dispatch order guarantees they run after GEMM blocks).
__global__ __launch_bounds__(512) void gemm1_kernel(const u16* __restrict__ xb,
                                                    const u16* __restrict__ W1T,
                                                    const float* __restrict__ b1,
                                                    const int* __restrict__ idxl,
                                                    const int* __restrict__ meta,
                                                    u16* __restrict__ h,
                                                    const float* __restrict__ W2,
                                                    u16* __restrict__ W2T) {
  __shared__ u16 sA[2][16384];
  __shared__ u16 sB[2][16384];
  const int bid = blockIdx.x;
  if (bid >= 1152) {
    // ---- W2 transpose tile: W2[ex] [HID][OUT] f32 -> W2T[ex] [OUT][HID] bf16 ----
    u16 (*tile)[72] = (u16(*)[72])&sA[0][0];
    const int ti = bid - 1152;           // [0, 6144)
    const int ex = ti >> 10;             // 1024 tiles per expert (16x x 64y)
    const int t2 = ti & 1023;
    const int tx = t2 & 15, ty = t2 >> 4;
    const float* src = W2 + (size_t)ex * HID_DIM * OUT_DIM;
    u16* dst = W2T + (size_t)ex * HID_DIM * OUT_DIM;
    const int C = OUT_DIM, R = HID_DIM;
    const int c0 = tx * 64, r0 = ty * 64;
    const int t = threadIdx.x;
    const int cc = (t & 15) * 4, rb = t >> 4;   // rb in [0,32)
#pragma unroll
    for (int p = 0; p < 2; p++) {
      int r = p * 32 + rb;
      float4 v = *(const float4*)(src + (size_t)(r0 + r) * C + c0 + cc);
      tile[cc + 0][r] = f2bf(v.x);
      tile[cc + 1][r] = f2bf(v.y);
      tile[cc + 2][r] = f2bf(v.z);
      tile[cc + 3][r] = f2bf(v.w);
    }
    __syncthreads();
    const int c = t >> 3, rp = (t & 7) * 8;
    *(u16x8*)(dst + (size_t)(c0 + c) * R + r0 + rp) = *(const u16x8*)&tile[c][rp];
    return;
  }
  const int xcd = bid & 7;
  const int s = bid >> 3;            // [0,144)
  const int chunk = s / 36, q = s % 36;
  const int n = chunk * 4 + (q & 3); // [0,16)
  const int mtg = xcd * 9 + (q >> 2);

  int e, mt, cnt;
  decode_expert(meta, mtg, e, mt, cnt);
  if (e < 0) return;
  const int off = meta[8 + e];
  const int bn0 = n * 256;
  const int tid = threadIdx.x, lane = tid & 63, wave = tid >> 6;
  const int wr = wave >> 2, wc = wave & 3;
  const int lrow = lane & 15, lhi = lane >> 4, lx7 = lane & 7;
  const int schunk = (lane & 7) ^ (lane >> 3);

  const u16* pa[2][2];
  const u16* pb[2][2];
  const u16* bbase = W1T + (size_t)e * HID_DIM * IN_DIM;
#pragma unroll
  for (int hh = 0; hh < 2; hh++)
#pragma unroll
    for (int i = 0; i < 2; i++) {
      int gr = hh * 128 + wave * 16 + i * 8 + (lane >> 3);
      int j = mt * 256 + gr; if (j >= cnt) j = cnt - 1;
      int tok = idxl[e * N_TOKENS + j];
      pa[hh][i] = xb + (size_t)tok * IN_DIM + schunk * 8;
      pb[hh][i] = bbase + (size_t)(bn0 + gr) * IN_DIM + schunk * 8;
    }

  f32x4 acc[2][2][4][2] = {};
  bf16x8 af[4][2], bfr[2][2];

  GEMM_KLOOP(IN_DIM / 64)

  // epilogue: relu(acc + b1) -> h (bf16)
#pragma unroll
  for (int ah = 0; ah < 2; ah++)
#pragma unroll
    for (int bh = 0; bh < 2; bh++)
#pragma unroll
      for (int nj = 0; nj < 2; nj++) {
        int col = bn0 + bh * 128 + wc * 32 + nj * 16 + lrow;
        float bias = b1[e * HID_DIM + col];
#pragma unroll
        for (int mi = 0; mi < 4; mi++)
#pragma unroll
          for (int rr = 0; rr < 4; rr++) {
            int j = mt * 256 + ah * 128 + wr * 64 + mi * 16 + lhi * 4 + rr;
            if (j < cnt) {
              float v = fmaxf(acc[ah][bh][mi][nj][rr] + bias, 0.f);
              h[(size_t)(off + j) * HID_DIM + col] = f2bf(v);
            }
          }
      }
}

// ---------------- grouped GEMM2: y_kz = (h @ W2 [+ b2 if kz==0]) as bf16, NO atomics ----------------
// XCD-chunked 1D grid (576 = 8v x 72m, v=(n,kz))
__global__ __launch_bounds__(512) void gemm2_kernel(const u16* __restrict__ hbuf,
                                                    const u16* __restrict__ W2T,
                                                    const float* __restrict__ b2,
                                                    const int* __restrict__ meta,
                                                    u16* __restrict__ y0,
                                                    u16* __restrict__ y1) {
  __shared__ u16 sA[2][16384];
  __shared__ u16 sB[2][16384];
  const int bid = blockIdx.x;
  const int xcd = bid & 7;
  const int s = bid >> 3;       // [0,72)
  const int v = s & 7;          // (n,kz) sibling, fastest
  const int mtg = xcd * 9 + (s >> 3);
  const int n = v >> 1, kzid = v & 1;

  int e, mt, cnt;
  decode_expert(meta, mtg, e, mt, cnt);
  if (e < 0) return;
  const int off = meta[8 + e];
  const int bn0 = n * 256;
  const int kz = kzid * (HID_DIM / 2);
  const int tid = threadIdx.x, lane = tid & 63, wave = tid >> 6;
  const int wr = wave >> 2, wc = wave & 3;
  const int lrow = lane & 15, lhi = lane >> 4, lx7 = lane & 7;
  const int schunk = (lane & 7) ^ (lane >> 3);

  const u16* pa[2][2];
  const u16* pb[2][2];
  const u16* bbase = W2T + (size_t)e * OUT_DIM * HID_DIM;
#pragma unroll
  for (int hh = 0; hh < 2; hh++)
#pragma unroll
    for (int i = 0; i < 2; i++) {
      int gr = hh * 128 + wave * 16 + i * 8 + (lane >> 3);
      int j = mt * 256 + gr; if (j >= cnt) j = cnt - 1;
      pa[hh][i] = hbuf + (size_t)(off + j) * HID_DIM + kz + schunk * 8;
      pb[hh][i] = bbase + (size_t)(bn0 + gr) * HID_DIM + kz + schunk * 8;
    }

  f32x4 acc[2][2][4][2] = {};
  bf16x8 af[4][2], bfr[2][2];

  GEMM_KLOOP(HID_DIM / 2 / 64)

  // epilogue: plain coalesced bf16 stores into the kz-specific y buffer
  u16* __restrict__ yb = kzid ? y1 : y0;
#pragma unroll
  for (int ah = 0; ah < 2; ah++)
#pragma unroll
    for (int bh = 0; bh < 2; bh++)
#pragma unroll
      for (int nj = 0; nj < 2; nj++) {
        int col = bn0 + bh * 128 + wc * 32 + nj * 16 + lrow;
        float bias = (kzid == 0) ? b2[e * OUT_DIM + col] : 0.f;
#pragma unroll
        for (int mi = 0; mi < 4; mi++)
#pragma unroll
          for (int rr = 0; rr < 4; rr++) {
            int j = mt * 256 + ah * 128 + wr * 64 + mi * 16 + lhi * 4 + rr;
            if (j < cnt)
              yb[(size_t)(off + j) * OUT_DIM + col] = f2bf(acc[ah][bh][mi][nj][rr] + bias);
          }
      }
}

// ---------------- combine: out[t] = sum_k w_k * (y0[slot_k] + y1[slot_k]) ----------------
__global__ __launch_bounds__(256) void combine_kernel(const u16* __restrict__ y0,
                                                      const u16* __restrict__ y1,
                                                      const int* __restrict__ gate_e,
                                                      const float* __restrict__ gate_w,
                                                      const int* __restrict__ tokslot,
                                                      const int* __restrict__ meta,
                                                      float* __restrict__ out) {
  const int t = blockIdx.x;
  const int e0 = gate_e[2 * t], e1 = gate_e[2 * t + 1];
  const float w0 = gate_w[2 * t], w1 = gate_w[2 * t + 1];
  const size_t s0 = (size_t)(meta[8 + e0] + tokslot[2 * t]) * OUT_DIM;
  const size_t s1 = (size_t)(meta[8 + e1] + tokslot[2 * t + 1]) * OUT_DIM;
  const int c = threadIdx.x * 4;
  u16x4 a0 = *(const u16x4*)(y0 + s0 + c);
  u16x4 b0 = *(const u16x4*)(y1 + s0 + c);
  u16x4 a1 = *(const u16x4*)(y0 + s1 + c);
  u16x4 b1 = *(const u16x4*)(y1 + s1 + c);
  float4 o;
  o.x = w0 * (bf2f(a0[0]) + bf2f(b0[0])) + w1 * (bf2f(a1[0]) + bf2f(b1[0]));
  o.y = w0 * (bf2f(a0[1]) + bf2f(b0[1])) + w1 * (bf2f(a1[1]) + bf2f(b1[1]));
  o.z = w0 * (bf2f(a0[2]) + bf2f(b0[2])) + w1 * (bf2f(a1[2]) + bf2f(b1[2]));
  o.w = w0 * (bf2f(a0[3]) + bf2f(b0[3])) + w1 * (bf2f(a1[3]) + bf2f(b1[3]));
  *(float4*)(out + (size_t)t * OUT_DIM + c) = o;
}

extern "C" void kernel_launch(void* const* d_in, const int* in_sizes, int n_in,
                              void* d_out, int out_size, void* d_ws, size_t ws_size,
                              hipStream_t stream) {
  const float* x  = (const float*)d_in[0];
  const float* Wg = (const float*)d_in[1];
  const float* bg = (const float*)d_in[2];
  const float* W1 = (const float*)d_in[3];
  const float* b1 = (const float*)d_in[4];
  const float* W2 = (const float*)d_in[5];
  const float* b2 = (const float*)d_in[6];
  float* out = (float*)d_out;

  char* ws = (char*)d_ws;
  // ws layout (bytes), r10-proven. y0/y1 ALIAS xb+W1T (dead after gemm1).
  u16*   xb     = (u16*)(ws);                         // 16,777,216   [live: prep..gemm1]
  u16*   W1T    = (u16*)(ws + 16777216);              // 50,331,648   [live: prep..gemm1]
  u16*   y0     = (u16*)(ws);                         // 33,554,432   [live: gemm2..combine]
  u16*   y1     = (u16*)(ws + 33554432);              // 33,554,432   [live: gemm2..combine]
  u16*   W2T    = (u16*)(ws + 67108864);              // 50,331,648   [written in gemm1 tail blocks]
  u16*   h      = (u16*)(ws + 117440512);             // 134,217,728
  int*   gate_e = (int*)(ws + 251658240);             // 65,536
  float* gate_w = (float*)(ws + 251723776);           // 65,536
  int*   idxl   = (int*)(ws + 251789312);             // 196,608
  int*   tokslot= (int*)(ws + 251985920);             // 65,536
  int*   meta   = (int*)(ws + 252051456);             // 64

  // prep: W1 transpose (6144 blocks) + gating/cvt (2048 blocks)
  prep_kernel<<<8192, 256, 0, stream>>>(W1, W1T, x, Wg, bg, xb, gate_e, gate_w);
  routing_kernel<<<1, 384, 0, stream>>>(gate_e, idxl, tokslot, meta);
  // gemm1: 1152 GEMM blocks + 6144 W2-transpose blocks (tail-filled)
  gemm1_kernel<<<7296, 512, 0, stream>>>(xb, W1T, b1, idxl, meta, h, W2, W2T);
  // gemm2: 8 (n,kz) x 72 padded m-tiles, XCD-chunked 1D; writes y0/y1
  gemm2_kernel<<<576, 512, 0, stream>>>(h, W2T, b2, meta, y0, y1);
  // combine: one block per token
  combine_kernel<<<N_TOKENS, 256, 0, stream>>>(y0, y1, gate_e, gate_w, tokslot, meta, out);
}